// Round 7
// baseline (132.230 us; speedup 1.0000x reference)
//
#include <hip/hip_runtime.h>
#include <math.h>

#define N_NODES 1024
#define N_EDGES 32768
#define FEAT    384
#define INV_S   0.05103103630798287f   // 1/sqrt(384)

// ---------------------------------------------------------------------------
// K1: q,k,v = feat @ {Wq,Wk,Wv}.  256 blocks x 384 thr, 4 rows/block.
// ---------------------------------------------------------------------------
__global__ __launch_bounds__(384) void k_kqv(
        const float* __restrict__ feat,
        const float* __restrict__ Wk, const float* __restrict__ Wq,
        const float* __restrict__ Wv,
        float* __restrict__ q, float* __restrict__ k, float* __restrict__ v) {
    __shared__ float fs[4 * FEAT];
    const int tid = threadIdx.x;
    const int row0 = blockIdx.x * 4;
    ((float4*)fs)[tid] = ((const float4*)(feat + (size_t)row0 * FEAT))[tid];
    __syncthreads();
    const int mat = tid >> 7;           // 0=q, 1=k, 2=v (128 threads each)
    const int sub = tid & 127;
    const int col = sub & 63;
    const int rh  = sub >> 6;           // rows rh*2, rh*2+1
    const float* W  = (mat == 0) ? Wq : (mat == 1 ? Wk : Wv);
    const float* f0 = fs + (rh * 2) * FEAT;
    const float* f1 = fs + (rh * 2 + 1) * FEAT;
    float a0 = 0.f, a1 = 0.f;
    #pragma unroll 8
    for (int f = 0; f < FEAT; ++f) {
        float wv = W[f * 64 + col];
        a0 = fmaf(f0[f], wv, a0);
        a1 = fmaf(f1[f], wv, a1);
    }
    float* out = (mat == 0) ? q : (mat == 1 ? k : v);
    out[(row0 + rh * 2 + 0) * 64 + col] = a0;
    out[(row0 + rh * 2 + 1) * 64 + col] = a1;
}

// ---------------------------------------------------------------------------
// K2: A = 2 * q @ k^T (logits).  64x64 tile/block, 4x4 microtile, padded LDS.
// ---------------------------------------------------------------------------
__global__ __launch_bounds__(256) void k_qkt(
        const float* __restrict__ q, const float* __restrict__ k,
        float* __restrict__ A) {
    __shared__ float qs[64][65];
    __shared__ float kst[64][65];   // kst[kk][col]
    const int tid = threadIdx.x;
    const int rowbase = blockIdx.y * 64, colbase = blockIdx.x * 64;
    for (int idx = tid; idx < 4096; idx += 256) {
        int r = idx >> 6, c = idx & 63;
        qs[r][c] = q[(rowbase + r) * 64 + c];
        kst[c][r] = k[(colbase + r) * 64 + c];
    }
    __syncthreads();
    const int tx = tid & 15, ty = tid >> 4;
    float acc[4][4] = {};
    for (int kk = 0; kk < 64; ++kk) {
        float a0 = qs[ty * 4 + 0][kk], a1 = qs[ty * 4 + 1][kk];
        float a2 = qs[ty * 4 + 2][kk], a3 = qs[ty * 4 + 3][kk];
        float b0 = kst[kk][tx * 4 + 0], b1 = kst[kk][tx * 4 + 1];
        float b2 = kst[kk][tx * 4 + 2], b3 = kst[kk][tx * 4 + 3];
        acc[0][0] = fmaf(a0, b0, acc[0][0]); acc[0][1] = fmaf(a0, b1, acc[0][1]);
        acc[0][2] = fmaf(a0, b2, acc[0][2]); acc[0][3] = fmaf(a0, b3, acc[0][3]);
        acc[1][0] = fmaf(a1, b0, acc[1][0]); acc[1][1] = fmaf(a1, b1, acc[1][1]);
        acc[1][2] = fmaf(a1, b2, acc[1][2]); acc[1][3] = fmaf(a1, b3, acc[1][3]);
        acc[2][0] = fmaf(a2, b0, acc[2][0]); acc[2][1] = fmaf(a2, b1, acc[2][1]);
        acc[2][2] = fmaf(a2, b2, acc[2][2]); acc[2][3] = fmaf(a2, b3, acc[2][3]);
        acc[3][0] = fmaf(a3, b0, acc[3][0]); acc[3][1] = fmaf(a3, b1, acc[3][1]);
        acc[3][2] = fmaf(a3, b2, acc[3][2]); acc[3][3] = fmaf(a3, b3, acc[3][3]);
    }
    for (int i = 0; i < 4; ++i) {
        float4 o = make_float4(2.f * acc[i][0], 2.f * acc[i][1],
                               2.f * acc[i][2], 2.f * acc[i][3]);
        *(float4*)&A[(size_t)(rowbase + ty * 4 + i) * N_NODES + colbase + tx * 4] = o;
    }
}

// ---------------------------------------------------------------------------
// K3: per-edge logit deltas: A[src,dst] += q[src].trunc(rk) + k[dst].trunc(rq)
// One wave per edge-group of 4 (embeddings hoisted), shuffle-reduce, 1 atomic.
// ---------------------------------------------------------------------------
__global__ __launch_bounds__(256) void k_edgeA(
        const int* __restrict__ ei, const float* __restrict__ eattr,
        const float* __restrict__ Ek, const float* __restrict__ Eq,
        const float* __restrict__ q, const float* __restrict__ k,
        const float* __restrict__ bias, const float* __restrict__ mult,
        float* __restrict__ A) {
    const int lane = threadIdx.x & 63;
    const int gw   = blockIdx.x * 4 + (threadIdx.x >> 6);   // 0..8191
    const float b0 = bias[0], mu = mult[0];
    const float ek0 = Ek[lane], ek1 = Ek[64 + lane];
    const float eq0 = Eq[lane], eq1 = Eq[64 + lane];
    #pragma unroll 2
    for (int i = 0; i < 4; ++i) {
        const int e = gw + i * 8192;
        const int src = ei[e], dst = ei[N_EDGES + e];
        const float w  = 1.0f / (1.0f + expf(-(eattr[e] - b0) * mu));
        const float rk = truncf(w * ek0 + (1.0f - w) * ek1);
        const float rq = truncf(w * eq0 + (1.0f - w) * eq1);
        float c = q[src * 64 + lane] * rk + k[dst * 64 + lane] * rq;
        #pragma unroll
        for (int off = 32; off >= 1; off >>= 1) c += __shfl_xor(c, off, 64);
        if (lane == 0) atomicAdd(&A[(size_t)src * N_NODES + dst], c);
    }
}

// ---------------------------------------------------------------------------
// K4: per-row softmax stats (m, 1/sum) from logits.  Wave per row.
// Block 0 additionally zeroes S[2048].  A itself is NOT modified.
// ---------------------------------------------------------------------------
__global__ __launch_bounds__(256) void k_stats(
        const float* __restrict__ A, float* __restrict__ rowstats,
        float* __restrict__ S) {
    const int tid = threadIdx.x, lane = tid & 63, wave = tid >> 6;
    if (blockIdx.x == 0)
        for (int i = tid; i < 2 * N_NODES; i += 256) S[i] = 0.f;
    const int row = blockIdx.x * 4 + wave;
    const float4* Ar = (const float4*)(A + (size_t)row * N_NODES);
    float4 x0 = Ar[lane * 4 + 0], x1 = Ar[lane * 4 + 1];
    float4 x2 = Ar[lane * 4 + 2], x3 = Ar[lane * 4 + 3];
    float m = fmaxf(fmaxf(fmaxf(x0.x, x0.y), fmaxf(x0.z, x0.w)),
                    fmaxf(fmaxf(x1.x, x1.y), fmaxf(x1.z, x1.w)));
    m = fmaxf(m, fmaxf(fmaxf(fmaxf(x2.x, x2.y), fmaxf(x2.z, x2.w)),
                       fmaxf(fmaxf(x3.x, x3.y), fmaxf(x3.z, x3.w))));
    #pragma unroll
    for (int off = 32; off >= 1; off >>= 1) m = fmaxf(m, __shfl_xor(m, off, 64));
    float s = expf((x0.x - m) * INV_S) + expf((x0.y - m) * INV_S)
            + expf((x0.z - m) * INV_S) + expf((x0.w - m) * INV_S)
            + expf((x1.x - m) * INV_S) + expf((x1.y - m) * INV_S)
            + expf((x1.z - m) * INV_S) + expf((x1.w - m) * INV_S)
            + expf((x2.x - m) * INV_S) + expf((x2.y - m) * INV_S)
            + expf((x2.z - m) * INV_S) + expf((x2.w - m) * INV_S)
            + expf((x3.x - m) * INV_S) + expf((x3.y - m) * INV_S)
            + expf((x3.z - m) * INV_S) + expf((x3.w - m) * INV_S);
    #pragma unroll
    for (int off = 32; off >= 1; off >>= 1) s += __shfl_xor(s, off, 64);
    if (lane == 0) {
        rowstats[row * 2 + 0] = m;
        rowstats[row * 2 + 1] = 1.0f / s;
    }
}

// ---------------------------------------------------------------------------
// K5: factorized value-embedding sums.  ONE THREAD PER EDGE:
//   prob = exp((logit-m)*inv_s)*rs;  S0[src] += prob*w;  S1[src] += prob*(1-w)
// 65K atomics total (vs 2.1M per-lane atomics of the old k_edgeM).
// ---------------------------------------------------------------------------
__global__ __launch_bounds__(256) void k_edgeS(
        const int* __restrict__ ei, const float* __restrict__ eattr,
        const float* __restrict__ A, const float* __restrict__ rowstats,
        const float* __restrict__ bias, const float* __restrict__ mult,
        float* __restrict__ S) {
    const int e = blockIdx.x * 256 + threadIdx.x;
    const int src = ei[e], dst = ei[N_EDGES + e];
    const float logit = A[(size_t)src * N_NODES + dst];
    const float m  = rowstats[src * 2 + 0];
    const float rs = rowstats[src * 2 + 1];
    const float prob = expf((logit - m) * INV_S) * rs;
    const float w = 1.0f / (1.0f + expf(-(eattr[e] - bias[0]) * mult[0]));
    atomicAdd(&S[src * 2 + 0], prob * w);
    atomicAdd(&S[src * 2 + 1], prob * (1.0f - w));
}

// ---------------------------------------------------------------------------
// K6: M = probs @ v + S0*Ev0 + S1*Ev1.  512 blocks x 2 rows.  Probs built in
// LDS from logits+stats; v read straight from L2 (coalesced line per j);
// j-range split across 4 waves; LDS reduce; direct store.
// ---------------------------------------------------------------------------
__global__ __launch_bounds__(256) void k_av(
        const float* __restrict__ A, const float* __restrict__ v,
        const float* __restrict__ rowstats, const float* __restrict__ S,
        const float* __restrict__ Ev, float* __restrict__ M) {
    __shared__ float P[2][1024];        // 8 KB probs
    __shared__ float red[2][4][64];     // 2 KB
    const int tid  = threadIdx.x;
    const int lane = tid & 63;
    const int wave = tid >> 6;
    const int row0 = blockIdx.x * 2;

    // probs: row g by 128 threads, 8 elems each
    {
        const int g  = tid >> 7;
        const int lt = tid & 127;
        const float m  = rowstats[(row0 + g) * 2 + 0];
        const float rs = rowstats[(row0 + g) * 2 + 1];
        const float4* Ar = (const float4*)(A + (size_t)(row0 + g) * N_NODES);
        float4 x0 = Ar[lt * 2], x1 = Ar[lt * 2 + 1];
        *(float4*)&P[g][lt * 8] = make_float4(
            expf((x0.x - m) * INV_S) * rs, expf((x0.y - m) * INV_S) * rs,
            expf((x0.z - m) * INV_S) * rs, expf((x0.w - m) * INV_S) * rs);
        *(float4*)&P[g][lt * 8 + 4] = make_float4(
            expf((x1.x - m) * INV_S) * rs, expf((x1.y - m) * INV_S) * rs,
            expf((x1.z - m) * INV_S) * rs, expf((x1.w - m) * INV_S) * rs);
    }
    __syncthreads();

    // AV: wave covers j-quarter, both rows; lane = output dim d
    {
        const float* vp = v + (size_t)(wave * 256) * 64 + lane;
        const float* p0 = &P[0][wave * 256];
        const float* p1 = &P[1][wave * 256];
        float acc0 = 0.f, acc1 = 0.f;
        #pragma unroll 2
        for (int j4 = 0; j4 < 256; j4 += 4) {
            float4 a0 = *(const float4*)&p0[j4];    // uniform addr: broadcast
            float4 a1 = *(const float4*)&p1[j4];
            float v0 = vp[(j4 + 0) * 64];
            float v1 = vp[(j4 + 1) * 64];
            float v2 = vp[(j4 + 2) * 64];
            float v3 = vp[(j4 + 3) * 64];
            acc0 = fmaf(a0.x, v0, acc0); acc0 = fmaf(a0.y, v1, acc0);
            acc0 = fmaf(a0.z, v2, acc0); acc0 = fmaf(a0.w, v3, acc0);
            acc1 = fmaf(a1.x, v0, acc1); acc1 = fmaf(a1.y, v1, acc1);
            acc1 = fmaf(a1.z, v2, acc1); acc1 = fmaf(a1.w, v3, acc1);
        }
        red[0][wave][lane] = acc0;
        red[1][wave][lane] = acc1;
    }
    __syncthreads();

    if (tid < 128) {
        const int r = tid >> 6, d = tid & 63;
        const int row = row0 + r;
        float acc = (red[r][0][d] + red[r][1][d]) + (red[r][2][d] + red[r][3][d]);
        acc += S[row * 2 + 0] * Ev[d] + S[row * 2 + 1] * Ev[64 + d];
        M[row * 64 + d] = acc;
    }
}

// ---------------------------------------------------------------------------
extern "C" void kernel_launch(void* const* d_in, const int* in_sizes, int n_in,
                              void* d_out, int out_size, void* d_ws, size_t ws_size,
                              hipStream_t stream) {
    (void)in_sizes; (void)n_in; (void)out_size; (void)ws_size;
    const float* feat  = (const float*)d_in[0];
    const int*   ei    = (const int*)d_in[1];
    const float* eattr = (const float*)d_in[2];
    const float* Wk    = (const float*)d_in[3];
    const float* Wq    = (const float*)d_in[4];
    const float* Wv    = (const float*)d_in[5];
    const float* Ek    = (const float*)d_in[6];
    const float* Eq    = (const float*)d_in[7];
    const float* Ev    = (const float*)d_in[8];
    const float* bias  = (const float*)d_in[9];
    const float* mult  = (const float*)d_in[10];
    float* M = (float*)d_out;

    float* wsf = (float*)d_ws;
    float* q        = wsf;                      // 1024*64
    float* k        = wsf + 65536;              // 1024*64
    float* v        = wsf + 131072;             // 1024*64
    float* A        = wsf + 196608;             // 1024*1024
    float* rowstats = wsf + 196608 + 1048576;   // 2048
    float* S        = rowstats + 2048;          // 2048

    k_kqv<<<256, 384, 0, stream>>>(feat, Wk, Wq, Wv, q, k, v);
    k_qkt<<<dim3(16, 16), 256, 0, stream>>>(q, k, A);
    k_edgeA<<<2048, 256, 0, stream>>>(ei, eattr, Ek, Eq, q, k, bias, mult, A);
    k_stats<<<256, 256, 0, stream>>>(A, rowstats, S);
    k_edgeS<<<128, 256, 0, stream>>>(ei, eattr, A, rowstats, bias, mult, S);
    k_av<<<512, 256, 0, stream>>>(A, v, rowstats, S, Ev, M);
}

// Round 8
// 123.825 us; speedup vs baseline: 1.0679x; 1.0679x over previous
//
#include <hip/hip_runtime.h>
#include <math.h>

#define N_NODES 1024
#define N_EDGES 32768
#define FEAT    384
#define INV_S   0.05103103630798287f   // 1/sqrt(384)
#define MAXH    1024                    // hit-list cap (mean 128, Poisson tail << 1024)

// ---------------------------------------------------------------------------
// K1: q,k,v = feat @ {Wq,Wk,Wv}.  256 blocks x 384 thr, 4 rows/block.
// ---------------------------------------------------------------------------
__global__ __launch_bounds__(384) void k_kqv(
        const float* __restrict__ feat,
        const float* __restrict__ Wk, const float* __restrict__ Wq,
        const float* __restrict__ Wv,
        float* __restrict__ q, float* __restrict__ k, float* __restrict__ v) {
    __shared__ float fs[4 * FEAT];
    const int tid = threadIdx.x;
    const int row0 = blockIdx.x * 4;
    ((float4*)fs)[tid] = ((const float4*)(feat + (size_t)row0 * FEAT))[tid];
    __syncthreads();
    const int mat = tid >> 7;           // 0=q, 1=k, 2=v (128 threads each)
    const int sub = tid & 127;
    const int col = sub & 63;
    const int rh  = sub >> 6;           // rows rh*2, rh*2+1
    const float* W  = (mat == 0) ? Wq : (mat == 1 ? Wk : Wv);
    const float* f0 = fs + (rh * 2) * FEAT;
    const float* f1 = fs + (rh * 2 + 1) * FEAT;
    float a0 = 0.f, a1 = 0.f;
    #pragma unroll 8
    for (int f = 0; f < FEAT; ++f) {
        float wv = W[f * 64 + col];
        a0 = fmaf(f0[f], wv, a0);
        a1 = fmaf(f1[f], wv, a1);
    }
    float* out = (mat == 0) ? q : (mat == 1 ? k : v);
    out[(row0 + rh * 2 + 0) * 64 + col] = a0;
    out[(row0 + rh * 2 + 1) * 64 + col] = a1;
}

// ---------------------------------------------------------------------------
// K2: A = 2 * q @ k^T (logits).  64x64 tile/block, 4x4 microtile, padded LDS.
// A is written exactly once here and is read-only afterwards.
// ---------------------------------------------------------------------------
__global__ __launch_bounds__(256) void k_qkt(
        const float* __restrict__ q, const float* __restrict__ k,
        float* __restrict__ A) {
    __shared__ float qs[64][65];
    __shared__ float kst[64][65];   // kst[kk][col]
    const int tid = threadIdx.x;
    const int rowbase = blockIdx.y * 64, colbase = blockIdx.x * 64;
    for (int idx = tid; idx < 4096; idx += 256) {
        int r = idx >> 6, c = idx & 63;
        qs[r][c] = q[(rowbase + r) * 64 + c];
        kst[c][r] = k[(colbase + r) * 64 + c];
    }
    __syncthreads();
    const int tx = tid & 15, ty = tid >> 4;
    float acc[4][4] = {};
    for (int kk = 0; kk < 64; ++kk) {
        float a0 = qs[ty * 4 + 0][kk], a1 = qs[ty * 4 + 1][kk];
        float a2 = qs[ty * 4 + 2][kk], a3 = qs[ty * 4 + 3][kk];
        float b0 = kst[kk][tx * 4 + 0], b1 = kst[kk][tx * 4 + 1];
        float b2 = kst[kk][tx * 4 + 2], b3 = kst[kk][tx * 4 + 3];
        acc[0][0] = fmaf(a0, b0, acc[0][0]); acc[0][1] = fmaf(a0, b1, acc[0][1]);
        acc[0][2] = fmaf(a0, b2, acc[0][2]); acc[0][3] = fmaf(a0, b3, acc[0][3]);
        acc[1][0] = fmaf(a1, b0, acc[1][0]); acc[1][1] = fmaf(a1, b1, acc[1][1]);
        acc[1][2] = fmaf(a1, b2, acc[1][2]); acc[1][3] = fmaf(a1, b3, acc[1][3]);
        acc[2][0] = fmaf(a2, b0, acc[2][0]); acc[2][1] = fmaf(a2, b1, acc[2][1]);
        acc[2][2] = fmaf(a2, b2, acc[2][2]); acc[2][3] = fmaf(a2, b3, acc[2][3]);
        acc[3][0] = fmaf(a3, b0, acc[3][0]); acc[3][1] = fmaf(a3, b1, acc[3][1]);
        acc[3][2] = fmaf(a3, b2, acc[3][2]); acc[3][3] = fmaf(a3, b3, acc[3][3]);
    }
    for (int i = 0; i < 4; ++i) {
        float4 o = make_float4(2.f * acc[i][0], 2.f * acc[i][1],
                               2.f * acc[i][2], 2.f * acc[i][3]);
        *(float4*)&A[(size_t)(rowbase + ty * 4 + i) * N_NODES + colbase + tx * 4] = o;
    }
}

// ---------------------------------------------------------------------------
// K3: per-4-rows mega kernel.  256 blocks x 512 thr.  Phases (in-block only):
//   1. load 4 logit rows -> LDS, q rows -> LDS
//   2. scan the full src list, collect edges with src in [row0,row0+4)
//   3. apply edge deltas q.trunc(rk)+k.trunc(rq) to LDS rows (LDS atomics)
//   4. softmax in LDS (stats + probs in place)
//   5. S0/S1 from the hit list (LDS atomics, ~128 hits)
//   6. M = probs @ v + S0*Ev0 + S1*Ev1, direct store
// No global atomics anywhere; A read-only; no CSR; no grid sync.
// ---------------------------------------------------------------------------
__global__ __launch_bounds__(512) void k_mega(
        const float* __restrict__ A0, const float* __restrict__ q,
        const float* __restrict__ k, const float* __restrict__ v,
        const int* __restrict__ ei, const float* __restrict__ eattr,
        const float* __restrict__ Ek, const float* __restrict__ Eq,
        const float* __restrict__ Ev,
        const float* __restrict__ bias, const float* __restrict__ mult,
        float* __restrict__ M) {
    __shared__ __align__(16) float As[4][N_NODES];      // 16 KB logits->probs
    __shared__ float qr[4][64];                         // 1 KB
    __shared__ __align__(16) float scratch[2048];       // 8 KB: list+wlist, then red
    __shared__ float redm[8], reds[8];
    __shared__ float sS[4][2];
    __shared__ int nhit;
    int*   list  = (int*)scratch;                       // phase 2-5: [0,1024)
    float* wlist = scratch + 1024;                      // phase 3-5: [1024,2048)
    float* red   = scratch;                             // phase 6: [4][8][64]

    const int tid  = threadIdx.x;
    const int lane = tid & 63;
    const int wave = tid >> 6;
    const int row0 = blockIdx.x * 4;

    if (tid < 8) ((float*)sS)[tid] = 0.f;
    if (tid == 8) nhit = 0;
    __syncthreads();

    // ---- phase 1: stage logit rows + q rows; phase 2: scan src list ----
    {
        const float4* src4 = (const float4*)(A0 + (size_t)row0 * N_NODES);
        #pragma unroll
        for (int i = 0; i < 2; ++i)
            ((float4*)As)[tid + i * 512] = src4[tid + i * 512];
        if (tid < 256) qr[tid >> 6][tid & 63] = q[row0 * 64 + tid];

        const int4* s4 = (const int4*)ei;               // src half of edge_index
        #pragma unroll 4
        for (int it = 0; it < 16; ++it) {
            const int i4 = tid + it * 512;
            const int4 sv = s4[i4];
            const int eb = i4 * 4;
            if ((unsigned)(sv.x - row0) < 4u) { int p = atomicAdd(&nhit, 1); if (p < MAXH) list[p] = eb + 0; }
            if ((unsigned)(sv.y - row0) < 4u) { int p = atomicAdd(&nhit, 1); if (p < MAXH) list[p] = eb + 1; }
            if ((unsigned)(sv.z - row0) < 4u) { int p = atomicAdd(&nhit, 1); if (p < MAXH) list[p] = eb + 2; }
            if ((unsigned)(sv.w - row0) < 4u) { int p = atomicAdd(&nhit, 1); if (p < MAXH) list[p] = eb + 3; }
        }
    }
    __syncthreads();
    const int nh = min(nhit, MAXH);

    // ---- phase 3: apply edge logit-deltas (one wave per hit edge) ----
    {
        const float b0 = bias[0], mu = mult[0];
        const float ek0 = Ek[lane], ek1 = Ek[64 + lane];
        const float eq0 = Eq[lane], eq1 = Eq[64 + lane];
        for (int i = wave; i < nh; i += 8) {
            const int e   = list[i];
            const int src = ei[e], dst = ei[N_EDGES + e];
            const float w  = 1.0f / (1.0f + expf(-(eattr[e] - b0) * mu));
            const float rk = truncf(w * ek0 + (1.0f - w) * ek1);
            const float rq = truncf(w * eq0 + (1.0f - w) * eq1);
            float c = qr[src - row0][lane] * rk + k[(size_t)dst * 64 + lane] * rq;
            #pragma unroll
            for (int off = 32; off >= 1; off >>= 1) c += __shfl_xor(c, off, 64);
            if (lane == 0) {
                atomicAdd(&As[src - row0][dst], c);
                wlist[i] = w;
            }
        }
    }
    __syncthreads();

    // ---- phase 4: softmax in LDS (row g by 128 threads, 8 elems each) ----
    const int g  = tid >> 7;
    const int lt = tid & 127;
    {
        float4 x0 = *(float4*)&As[g][lt * 8];
        float4 x1 = *(float4*)&As[g][lt * 8 + 4];
        float m = fmaxf(fmaxf(fmaxf(x0.x, x0.y), fmaxf(x0.z, x0.w)),
                        fmaxf(fmaxf(x1.x, x1.y), fmaxf(x1.z, x1.w)));
        #pragma unroll
        for (int off = 32; off >= 1; off >>= 1) m = fmaxf(m, __shfl_xor(m, off, 64));
        if (lane == 0) redm[wave] = m;
        __syncthreads();
        m = fmaxf(redm[g * 2], redm[g * 2 + 1]);
        float e0 = expf((x0.x - m) * INV_S), e1 = expf((x0.y - m) * INV_S);
        float e2 = expf((x0.z - m) * INV_S), e3 = expf((x0.w - m) * INV_S);
        float e4 = expf((x1.x - m) * INV_S), e5 = expf((x1.y - m) * INV_S);
        float e6 = expf((x1.z - m) * INV_S), e7 = expf((x1.w - m) * INV_S);
        float s = ((e0 + e1) + (e2 + e3)) + ((e4 + e5) + (e6 + e7));
        #pragma unroll
        for (int off = 32; off >= 1; off >>= 1) s += __shfl_xor(s, off, 64);
        if (lane == 0) reds[wave] = s;
        __syncthreads();
        s = reds[g * 2] + reds[g * 2 + 1];
        const float rs = 1.0f / s;
        *(float4*)&As[g][lt * 8]     = make_float4(e0 * rs, e1 * rs, e2 * rs, e3 * rs);
        *(float4*)&As[g][lt * 8 + 4] = make_float4(e4 * rs, e5 * rs, e6 * rs, e7 * rs);
    }
    __syncthreads();

    // ---- phase 5: S0/S1 from hit list (probs now in As) ----
    for (int i = tid; i < nh; i += 512) {
        const int e  = list[i];
        const int rl = ei[e] - row0, dst = ei[N_EDGES + e];
        const float pr = As[rl][dst];
        const float w  = wlist[i];
        atomicAdd(&sS[rl][0], pr * w);
        atomicAdd(&sS[rl][1], pr * (1.0f - w));
    }
    __syncthreads();        // list/wlist dead after this; red reuses scratch

    // ---- phase 6: M = probs @ v + S*Ev.  Wave w -> j in [w*128,(w+1)*128) ----
    {
        const float* vp = v + (size_t)(wave * 128) * 64 + lane;
        const float* p0 = &As[0][wave * 128];
        const float* p1 = &As[1][wave * 128];
        const float* p2 = &As[2][wave * 128];
        const float* p3 = &As[3][wave * 128];
        float a0 = 0.f, a1 = 0.f, a2 = 0.f, a3 = 0.f;
        #pragma unroll 2
        for (int j4 = 0; j4 < 128; j4 += 4) {
            float4 c0 = *(const float4*)&p0[j4];    // uniform addr: broadcast
            float4 c1 = *(const float4*)&p1[j4];
            float4 c2 = *(const float4*)&p2[j4];
            float4 c3 = *(const float4*)&p3[j4];
            float v0 = vp[(j4 + 0) * 64];
            float v1 = vp[(j4 + 1) * 64];
            float v2 = vp[(j4 + 2) * 64];
            float v3 = vp[(j4 + 3) * 64];
            a0 = fmaf(c0.x, v0, a0); a0 = fmaf(c0.y, v1, a0);
            a0 = fmaf(c0.z, v2, a0); a0 = fmaf(c0.w, v3, a0);
            a1 = fmaf(c1.x, v0, a1); a1 = fmaf(c1.y, v1, a1);
            a1 = fmaf(c1.z, v2, a1); a1 = fmaf(c1.w, v3, a1);
            a2 = fmaf(c2.x, v0, a2); a2 = fmaf(c2.y, v1, a2);
            a2 = fmaf(c2.z, v2, a2); a2 = fmaf(c2.w, v3, a2);
            a3 = fmaf(c3.x, v0, a3); a3 = fmaf(c3.y, v1, a3);
            a3 = fmaf(c3.z, v2, a3); a3 = fmaf(c3.w, v3, a3);
        }
        red[(0 * 8 + wave) * 64 + lane] = a0;
        red[(1 * 8 + wave) * 64 + lane] = a1;
        red[(2 * 8 + wave) * 64 + lane] = a2;
        red[(3 * 8 + wave) * 64 + lane] = a3;
    }
    __syncthreads();
    if (tid < 256) {
        const int r = tid >> 6, d = tid & 63;
        float acc = 0.f;
        #pragma unroll
        for (int w8 = 0; w8 < 8; ++w8) acc += red[(r * 8 + w8) * 64 + d];
        acc += sS[r][0] * Ev[d] + sS[r][1] * Ev[64 + d];
        M[(row0 + r) * 64 + d] = acc;
    }
}

// ---------------------------------------------------------------------------
extern "C" void kernel_launch(void* const* d_in, const int* in_sizes, int n_in,
                              void* d_out, int out_size, void* d_ws, size_t ws_size,
                              hipStream_t stream) {
    (void)in_sizes; (void)n_in; (void)out_size; (void)ws_size;
    const float* feat  = (const float*)d_in[0];
    const int*   ei    = (const int*)d_in[1];
    const float* eattr = (const float*)d_in[2];
    const float* Wk    = (const float*)d_in[3];
    const float* Wq    = (const float*)d_in[4];
    const float* Wv    = (const float*)d_in[5];
    const float* Ek    = (const float*)d_in[6];
    const float* Eq    = (const float*)d_in[7];
    const float* Ev    = (const float*)d_in[8];
    const float* bias  = (const float*)d_in[9];
    const float* mult  = (const float*)d_in[10];
    float* M = (float*)d_out;

    float* wsf = (float*)d_ws;
    float* q = wsf;                     // 1024*64
    float* k = wsf + 65536;             // 1024*64
    float* v = wsf + 131072;            // 1024*64
    float* A = wsf + 196608;            // 1024*1024 (logits, written once)

    k_kqv<<<256, 384, 0, stream>>>(feat, Wk, Wq, Wv, q, k, v);
    k_qkt<<<dim3(16, 16), 256, 0, stream>>>(q, k, A);
    k_mega<<<256, 512, 0, stream>>>(A, q, k, v, ei, eattr, Ek, Eq, Ev,
                                    bias, mult, M);
}